// Round 5
// baseline (240.332 us; speedup 1.0000x reference)
//
#include <hip/hip_runtime.h>
#include <stdint.h>

#define B_ 2
#define S_ 2048
#define DM_ 2048
#define H_ 32
#define KVH_ 8
#define HD_ 64
#define NQK_ 3072   // 2048 q + 512 k + 512 v

typedef unsigned short u16;
typedef unsigned int u32;
typedef __attribute__((ext_vector_type(8))) short bf16x8;
typedef __attribute__((ext_vector_type(4))) float f32x4;
typedef __attribute__((ext_vector_type(16))) float f32x16;
typedef __attribute__((ext_vector_type(4))) u32 u32x4;

static __device__ __forceinline__ u16 f2bf(float f) {
  unsigned int u = __float_as_uint(f);
  u = (u + 0x7fffu + ((u >> 16) & 1u)) >> 16;
  return (u16)u;
}
static __device__ __forceinline__ float bf2f(u16 v) {
  unsigned int u = ((unsigned int)v) << 16;
  return __uint_as_float(u);
}

// global -> LDS direct (width 16). LDS dest = wave-uniform base + lane*16.
static __device__ __forceinline__ void gload16(const void* g, void* lds_wave_base) {
  __builtin_amdgcn_global_load_lds(
      (__attribute__((address_space(1))) unsigned int*)(uintptr_t)g,
      (__attribute__((address_space(3))) unsigned int*)(uintptr_t)lds_wave_base,
      16, 0, 0);
}

// ---------------- fp32 -> bf16 convert ----------------
__global__ void cvt_bf16(const float* __restrict__ in, u16* __restrict__ out, int n4) {
  int i = blockIdx.x * blockDim.x + threadIdx.x;
  if (i >= n4) return;
  const float4 v = ((const float4*)in)[i];
  ushort4 o;
  o.x = f2bf(v.x); o.y = f2bf(v.y); o.z = f2bf(v.z); o.w = f2bf(v.w);
  ((ushort4*)out)[i] = o;
}

// ---------------- GEMM: C(MxN) = A(MxK) * B(NxK)^T, bf16 in ----------------
#define BM 128
#define BN 128
#define BK 32

#define GEMM_BODY(CSTORE)                                                       \
  __shared__ u16 As[2][BM * BK];                                                \
  __shared__ u16 Bs[2][BN * BK];                                                \
  const int t = threadIdx.x;                                                    \
  const int lane = t & 63;                                                      \
  const int w = t >> 6;                                                         \
  const int wr = (w >> 1) * 64, wc = (w & 1) * 64;                              \
  const int m0 = blockIdx.y * BM;                                               \
  const int n0 = blockIdx.x * BN;                                               \
  f32x4 acc[4][4] = {};                                                         \
  const char* Ab = (const char*)A;                                              \
  const char* Bb = (const char*)Bw;                                             \
  const size_t K2 = (size_t)K * 2;                                              \
  const int P0 = t * 16;                                                        \
  const int row0 = P0 >> 6, kb0 = P0 & 63;                                      \
  const int P1 = 4096 + t * 16;                                                 \
  const int row1 = P1 >> 6, kb1 = P1 & 63;                                      \
  const int Pb0 = (w << 10), Pb1 = 4096 + (w << 10);                            \
  auto STAGE = [&](int buf, int k0) {                                           \
    gload16(Ab + (size_t)(m0 + row0) * K2 + (size_t)k0 * 2 + kb0, (char*)As[buf] + Pb0); \
    gload16(Ab + (size_t)(m0 + row1) * K2 + (size_t)k0 * 2 + kb1, (char*)As[buf] + Pb1); \
    gload16(Bb + (size_t)(n0 + row0) * K2 + (size_t)k0 * 2 + kb0, (char*)Bs[buf] + Pb0); \
    gload16(Bb + (size_t)(n0 + row1) * K2 + (size_t)k0 * 2 + kb1, (char*)Bs[buf] + Pb1); \
  };                                                                            \
  STAGE(0, 0);                                                                  \
  __syncthreads();                                                              \
  int cur = 0;                                                                  \
  for (int k0 = 0; k0 < K; k0 += BK) {                                          \
    if (k0 + BK < K) STAGE(cur ^ 1, k0 + BK);                                   \
    bf16x8 af[4], bfr[4];                                                       \
    _Pragma("unroll")                                                           \
    for (int m = 0; m < 4; m++)                                                 \
      af[m] = *(const bf16x8*)((const char*)As[cur] +                           \
               (wr + m * 16 + (lane & 15)) * 64 + ((lane >> 4) << 4));          \
    _Pragma("unroll")                                                           \
    for (int n = 0; n < 4; n++)                                                 \
      bfr[n] = *(const bf16x8*)((const char*)Bs[cur] +                          \
               (wc + n * 16 + (lane & 15)) * 64 + ((lane >> 4) << 4));          \
    _Pragma("unroll")                                                           \
    for (int m = 0; m < 4; m++)                                                 \
      _Pragma("unroll")                                                         \
      for (int n = 0; n < 4; n++)                                               \
        acc[m][n] = __builtin_amdgcn_mfma_f32_16x16x32_bf16(af[m], bfr[n], acc[m][n], 0, 0, 0); \
    __syncthreads();                                                            \
    cur ^= 1;                                                                   \
  }                                                                             \
  _Pragma("unroll")                                                             \
  for (int m = 0; m < 4; m++) {                                                 \
    const int r0 = m0 + wr + m * 16 + ((lane >> 4) << 2);                       \
    _Pragma("unroll")                                                           \
    for (int n = 0; n < 4; n++) {                                               \
      const int c = n0 + wc + n * 16 + (lane & 15);                             \
      _Pragma("unroll")                                                         \
      for (int j = 0; j < 4; j++) CSTORE;                                       \
    }                                                                           \
  }

__global__ __launch_bounds__(256) void gemm_bt(const u16* __restrict__ A,
                                               const u16* __restrict__ Bw,
                                               float* __restrict__ C,
                                               int M, int N, int K) {
  GEMM_BODY(C[(size_t)(r0 + j) * N + c] = acc[m][n][j])
}

__global__ __launch_bounds__(256) void gemm_btb(const u16* __restrict__ A,
                                                const u16* __restrict__ Bw,
                                                u16* __restrict__ C,
                                                int M, int N, int K) {
  GEMM_BODY(C[(size_t)(r0 + j) * N + c] = f2bf(acc[m][n][j]))
}

// ------- fused RMSNorm + RoPE, in-place on bf16 QKV buffer ------------------
__global__ void norm_rope_inplace(u16* __restrict__ QKV, const float* __restrict__ cosT,
                                  const float* __restrict__ sinT,
                                  const float* __restrict__ qw,
                                  const float* __restrict__ kw, float qscale) {
  const int r = blockIdx.x * 4 + (threadIdx.x >> 6);
  const int lane = threadIdx.x & 63;
  const int hh2 = r % 40;
  const int bs = r / 40;
  const int s = bs & (S_ - 1);
  const bool isq = hh2 < 32;
  u16* p = QKV + (size_t)bs * NQK_ + hh2 * 64 + lane;
  float x = bf2f(*p);
  float ss = x * x;
#pragma unroll
  for (int m = 1; m < 64; m <<= 1) ss += __shfl_xor(ss, m, 64);
  const float wgt = isq ? qw[lane] : kw[lane];
  float xn = x * rsqrtf(ss * (1.0f / 64.0f) + 1e-6f) * wgt;
  float pr = __shfl_xor(xn, 32, 64);
  float o = xn * cosT[s * 64 + lane] + (lane < 32 ? -pr : pr) * sinT[s * 64 + lane];
  *p = f2bf(o * (isq ? qscale : 1.0f));
}

// -------- V: bf16 QKV v-part (b,s,kvh,d) -> bf16 (b,kvh,d,s) ---------------
__global__ void v_transpose(const u16* __restrict__ QKV, u16* __restrict__ Vt) {
  __shared__ u16 tile[64][72];
  const int s0 = blockIdx.x * 64;
  const int bk = blockIdx.y;
  const int b = bk / KVH_, kvh = bk % KVH_;
  const int t = threadIdx.x;
#pragma unroll
  for (int it = 0; it < 16; it++) {
    int idx = it * 256 + t;
    int sl = idx >> 6, d = idx & 63;
    tile[sl][d] = QKV[(size_t)(b * S_ + s0 + sl) * NQK_ + 2560 + kvh * 64 + d];
  }
  __syncthreads();
#pragma unroll
  for (int it = 0; it < 16; it++) {
    int idx = it * 256 + t;
    int d = idx >> 6, sl = idx & 63;
    Vt[(((size_t)(b * KVH_ + kvh)) * HD_ + d) * S_ + s0 + sl] = tile[sl][d];
  }
}

// ---------------- flash attention, causal GQA, 32x32 MFMA -------------------
// 4 waves x QBLK=32; each wave owns one low + one high q-tile sharing one kt
// loop (shared K/V staging + LDS fragment reads). P never touches LDS:
// cvt_pk + permlane32_swap reshape QK accumulators into PV A-fragments.
__global__ __launch_bounds__(256, 2) void attn_fwd(const u16* __restrict__ QKV,
                                                   const u16* __restrict__ Vt,
                                                   u16* __restrict__ Out) {
  __shared__ u16 Ksm[2][64 * 64];   // [key][d], XOR-swizzled 128B rows
  __shared__ u16 Vsm[2][64 * 64];   // [d][key], XOR-swizzled 128B rows

  const int t = threadIdx.x, lane = t & 63, w = t >> 6;
  const int q31 = lane & 31, hi = lane >> 5;

  // XCD-aware decode: 64 consecutive fids share one XCD -> 2 (b,kvh) panels.
  const int fid = blockIdx.x;                 // 0..511
  const int xcd = fid & 7, slot = fid >> 3;   // slot 0..63
  const int kg = xcd * 2 + (slot >> 5);       // (b,kvh) 0..15
  const int sub = slot & 31;
  const int b = kg >> 3, kvh = kg & 7;
  const int h = kvh * 4 + (sub & 3);
  const int ip = sub >> 2;                    // supertile pair 0..7

  const int qlo0 = ip * 128 + w * 32;         // low q-tile base row
  const int qhi0 = (15 - ip) * 128 + w * 32;  // high q-tile base row
  const int ktlo_max = (qlo0 + 31) >> 6;
  const int kthi_max = (qhi0 + 31) >> 6;
  const int KT = (15 - ip) * 2 + 1;           // block-uniform loop bound

  const char* Kb = (const char*)(QKV + (size_t)b * S_ * NQK_ + 2048 + kvh * 64);
  const char* Vb = (const char*)(Vt + ((size_t)(b * KVH_ + kvh)) * HD_ * S_);

  // staging (linear LDS dest, inverse-swizzled global source)
  const int SP0 = t * 16, SP1 = 4096 + t * 16;
  const int srow0 = SP0 >> 7, scb0 = (SP0 ^ ((srow0 & 7) << 4)) & 127;
  const int srow1 = SP1 >> 7, scb1 = (SP1 ^ ((srow1 & 7) << 4)) & 127;
  const int SB0 = (w << 10), SB1 = 4096 + (w << 10);
  const size_t KROW = (size_t)NQK_ * 2;

  auto STAGE = [&](int buf, int kt) {
    gload16(Kb + (size_t)(kt * 64 + srow0) * KROW + scb0, (char*)Ksm[buf] + SB0);
    gload16(Kb + (size_t)(kt * 64 + srow1) * KROW + scb1, (char*)Ksm[buf] + SB1);
    gload16(Vb + (size_t)srow0 * (S_ * 2) + (size_t)kt * 128 + scb0, (char*)Vsm[buf] + SB0);
    gload16(Vb + (size_t)srow1 * (S_ * 2) + (size_t)kt * 128 + scb1, (char*)Vsm[buf] + SB1);
  };

  // Q fragments: B-operand, lane holds col q=q31, d = sl*16 + hi*8 + j
  bf16x8 qf0[4], qf1[4];
  {
    const u16* qp0 = QKV + (size_t)(b * S_ + qlo0 + q31) * NQK_ + h * 64 + hi * 8;
    const u16* qp1 = QKV + (size_t)(b * S_ + qhi0 + q31) * NQK_ + h * 64 + hi * 8;
#pragma unroll
    for (int sl = 0; sl < 4; sl++) {
      qf0[sl] = *(const bf16x8*)(qp0 + sl * 16);
      qf1[sl] = *(const bf16x8*)(qp1 + sl * 16);
    }
  }

  bf16x8 ones;
#pragma unroll
  for (int j = 0; j < 8; j++) ones[j] = (short)0x3F80;

  f32x16 o00 = {}, o01 = {}, o10 = {}, o11 = {};  // o[qt][dtile]
  f32x16 l0 = {}, l1 = {};
  float m0 = -1e30f, m1 = -1e30f;

  auto cvtpk = [](float a, float bb) {
    u32 r;
    asm("v_cvt_pk_bf16_f32 %0, %1, %2" : "=v"(r) : "v"(a), "v"(bb));
    return r;
  };

  STAGE(0, 0);
  __syncthreads();
  int cur = 0;

  for (int kt = 0; kt <= KT; kt++) {
    if (kt < KT) STAGE(cur ^ 1, kt + 1);

    // K fragments (A-operand): key = kh*32 + q31, d = sl*16 + hi*8 + j
    bf16x8 kf[2][4];
#pragma unroll
    for (int kh = 0; kh < 2; kh++)
#pragma unroll
      for (int sl = 0; sl < 4; sl++) {
        const int row = kh * 32 + q31;
        const int byt = (row * 128 + sl * 32 + hi * 16) ^ ((row & 7) << 4);
        kf[kh][sl] = *(const bf16x8*)((const char*)Ksm[cur] + byt);
      }

    bf16x8 pa0[4], pa1[4];
    const bool act0 = (kt <= ktlo_max);
    const bool act1 = (kt <= kthi_max);

    // ---- per-q-tile: QK^T -> mask -> softmax -> PA fragments ----
#define QTILE(ACT, QF, PA, MI, LI, OA, OB, Q0, KTMAX)                           \
    if (ACT) {                                                                  \
      f32x16 p0 = {}, p1 = {};                                                  \
      __builtin_amdgcn_s_setprio(1);                                            \
      _Pragma("unroll")                                                         \
      for (int sl = 0; sl < 4; sl++) {                                          \
        p0 = __builtin_amdgcn_mfma_f32_32x32x16_bf16(kf[0][sl], QF[sl], p0, 0, 0, 0); \
        p1 = __builtin_amdgcn_mfma_f32_32x32x16_bf16(kf[1][sl], QF[sl], p1, 0, 0, 0); \
      }                                                                         \
      __builtin_amdgcn_s_setprio(0);                                            \
      if (kt == KTMAX) {                                                        \
        const int qg = Q0 + q31;                                                \
        _Pragma("unroll")                                                       \
        for (int r = 0; r < 16; r++) {                                          \
          const int crow = (r & 3) + 8 * (r >> 2) + 4 * hi;                     \
          if (kt * 64 + crow > qg) p0[r] = -1e30f;                              \
          if (kt * 64 + 32 + crow > qg) p1[r] = -1e30f;                         \
        }                                                                       \
      }                                                                         \
      float mx = fmaxf(p0[0], p1[0]);                                           \
      _Pragma("unroll")                                                         \
      for (int r = 1; r < 16; r++) mx = fmaxf(mx, fmaxf(p0[r], p1[r]));         \
      mx = fmaxf(mx, __shfl_xor(mx, 32, 64));                                   \
      if (!__all(mx <= MI + 8.0f)) {                                            \
        const float mn = fmaxf(MI, mx);                                         \
        const float al = exp2f(MI - mn);                                        \
        MI = mn;                                                                \
        _Pragma("unroll")                                                       \
        for (int r = 0; r < 16; r++) {                                          \
          const float aO = __shfl(al, (r & 3) + 8 * (r >> 2) + 4 * hi, 64);     \
          LI[r] *= aO; OA[r] *= aO; OB[r] *= aO;                                \
        }                                                                       \
      }                                                                         \
      _Pragma("unroll")                                                         \
      for (int r = 0; r < 16; r++) {                                            \
        p0[r] = exp2f(p0[r] - MI);                                              \
        p1[r] = exp2f(p1[r] - MI);                                              \
      }                                                                         \
      u32 wa, wb2, wc2, wd;                                                     \
      union { u32x4 u; bf16x8 h; } cv;                                          \
      wa = cvtpk(p0[0], p0[1]);  wb2 = cvtpk(p0[2], p0[3]);                     \
      wc2 = cvtpk(p0[4], p0[5]); wd = cvtpk(p0[6], p0[7]);                      \
      asm("v_permlane32_swap_b32 %0, %1" : "+v"(wa), "+v"(wc2));                \
      asm("v_permlane32_swap_b32 %0, %1" : "+v"(wb2), "+v"(wd));                \
      cv.u[0] = wa; cv.u[1] = wb2; cv.u[2] = wc2; cv.u[3] = wd; PA[0] = cv.h;   \
      wa = cvtpk(p0[8], p0[9]);   wb2 = cvtpk(p0[10], p0[11]);                  \
      wc2 = cvtpk(p0[12], p0[13]); wd = cvtpk(p0[14], p0[15]);                  \
      asm("v_permlane32_swap_b32 %0, %1" : "+v"(wa), "+v"(wc2));                \
      asm("v_permlane32_swap_b32 %0, %1" : "+v"(wb2), "+v"(wd));                \
      cv.u[0] = wa; cv.u[1] = wb2; cv.u[2] = wc2; cv.u[3] = wd; PA[1] = cv.h;   \
      wa = cvtpk(p1[0], p1[1]);  wb2 = cvtpk(p1[2], p1[3]);                     \
      wc2 = cvtpk(p1[4], p1[5]); wd = cvtpk(p1[6], p1[7]);                      \
      asm("v_permlane32_swap_b32 %0, %1" : "+v"(wa), "+v"(wc2));                \
      asm("v_permlane32_swap_b32 %0, %1" : "+v"(wb2), "+v"(wd));                \
      cv.u[0] = wa; cv.u[1] = wb2; cv.u[2] = wc2; cv.u[3] = wd; PA[2] = cv.h;   \
      wa = cvtpk(p1[8], p1[9]);   wb2 = cvtpk(p1[10], p1[11]);                  \
      wc2 = cvtpk(p1[12], p1[13]); wd = cvtpk(p1[14], p1[15]);                  \
      asm("v_permlane32_swap_b32 %0, %1" : "+v"(wa), "+v"(wc2));                \
      asm("v_permlane32_swap_b32 %0, %1" : "+v"(wb2), "+v"(wd));                \
      cv.u[0] = wa; cv.u[1] = wb2; cv.u[2] = wc2; cv.u[3] = wd; PA[3] = cv.h;   \
    }

    QTILE(act0, qf0, pa0, m0, l0, o00, o01, qlo0, ktlo_max)
    QTILE(act1, qf1, pa1, m1, l1, o10, o11, qhi0, kthi_max)
#undef QTILE

    // V fragments (B-operand): col d = dt*32 + q31, k = sl*16 + hi*8 + j
    bf16x8 vf[4][2];
#pragma unroll
    for (int sl = 0; sl < 4; sl++)
#pragma unroll
      for (int dt = 0; dt < 2; dt++) {
        const int row = dt * 32 + q31;
        const int byt = (row * 128 + sl * 32 + hi * 16) ^ ((row & 7) << 4);
        vf[sl][dt] = *(const bf16x8*)((const char*)Vsm[cur] + byt);
      }

    __builtin_amdgcn_s_setprio(1);
    if (act0) {
#pragma unroll
      for (int sl = 0; sl < 4; sl++) {
        l0 = __builtin_amdgcn_mfma_f32_32x32x16_bf16(pa0[sl], ones, l0, 0, 0, 0);
        o00 = __builtin_amdgcn_mfma_f32_32x32x16_bf16(pa0[sl], vf[sl][0], o00, 0, 0, 0);
        o01 = __builtin_amdgcn_mfma_f32_32x32x16_bf16(pa0[sl], vf[sl][1], o01, 0, 0, 0);
      }
    }
    if (act1) {
#pragma unroll
      for (int sl = 0; sl < 4; sl++) {
        l1 = __builtin_amdgcn_mfma_f32_32x32x16_bf16(pa1[sl], ones, l1, 0, 0, 0);
        o10 = __builtin_amdgcn_mfma_f32_32x32x16_bf16(pa1[sl], vf[sl][0], o10, 0, 0, 0);
        o11 = __builtin_amdgcn_mfma_f32_32x32x16_bf16(pa1[sl], vf[sl][1], o11, 0, 0, 0);
      }
    }
    __builtin_amdgcn_s_setprio(0);

    __syncthreads();
    cur ^= 1;
  }

  // epilogue: O /= l (O-domain rows), write bf16 (b,s,h,d)
#pragma unroll
  for (int r = 0; r < 16; r++) {
    const int crow = (r & 3) + 8 * (r >> 2) + 4 * hi;
    {
      const int qg = qlo0 + crow;
      const float inv = 1.0f / l0[r];
      u16* op = Out + (((size_t)(b * S_ + qg)) * H_ + h) * HD_;
      op[q31] = f2bf(o00[r] * inv);
      op[32 + q31] = f2bf(o01[r] * inv);
    }
    {
      const int qg = qhi0 + crow;
      const float inv = 1.0f / l1[r];
      u16* op = Out + (((size_t)(b * S_ + qg)) * H_ + h) * HD_;
      op[q31] = f2bf(o10[r] * inv);
      op[32 + q31] = f2bf(o11[r] * inv);
    }
  }
}

// ---------------- host launch ----------------
extern "C" void kernel_launch(void* const* d_in, const int* in_sizes, int n_in,
                              void* d_out, int out_size, void* d_ws, size_t ws_size,
                              hipStream_t stream) {
  const float* x  = (const float*)d_in[0];
  const float* rc = (const float*)d_in[1];
  const float* rs = (const float*)d_in[2];
  const float* Wq = (const float*)d_in[3];
  const float* Wk = (const float*)d_in[4];
  const float* Wv = (const float*)d_in[5];
  const float* Wo = (const float*)d_in[6];
  const float* qw = (const float*)d_in[7];
  const float* kw = (const float*)d_in[8];
  float* out = (float*)d_out;

  char* ws = (char*)d_ws;
  const size_t MB = (size_t)1 << 20;
  u16* xb   = (u16*)(ws + 0 * MB);    // 16 MB bf16 x (reused as attn-out)
  u16* wbq  = (u16*)(ws + 16 * MB);   // 12 MB bf16 [Wq;Wk;Wv] (then Wo reuse)
  u16* QKVb = (u16*)(ws + 28 * MB);   // 24 MB bf16 QKV proj (b,s,3072)
  u16* Vtb  = (u16*)(ws + 52 * MB);   // 4 MB  bf16 V (b,kvh,d,s)
  u16* AO   = xb;

  const int MT = B_ * S_;
  const float QSC = 0.125f * 1.44269504089f;  // (1/sqrt(64)) * log2(e)

  cvt_bf16<<<dim3(MT * DM_ / 1024), 256, 0, stream>>>(x, xb, MT * DM_ / 4);
  cvt_bf16<<<dim3(DM_ * DM_ / 1024), 256, 0, stream>>>(Wq, wbq, DM_ * DM_ / 4);
  cvt_bf16<<<dim3(512 * DM_ / 1024), 256, 0, stream>>>(Wk, wbq + (size_t)DM_ * DM_, 512 * DM_ / 4);
  cvt_bf16<<<dim3(512 * DM_ / 1024), 256, 0, stream>>>(Wv, wbq + (size_t)DM_ * DM_ + (size_t)512 * DM_, 512 * DM_ / 4);

  gemm_btb<<<dim3(NQK_ / BN, MT / BM), 256, 0, stream>>>(xb, wbq, QKVb, MT, NQK_, DM_);

  norm_rope_inplace<<<dim3(MT * 40 / 4), 256, 0, stream>>>(QKVb, rc, rs, qw, kw, QSC);

  v_transpose<<<dim3(S_ / 64, B_ * KVH_), 256, 0, stream>>>(QKVb, Vtb);

  // attention: 512 blocks (2/CU), 4 waves x (one low + one high 32-row q-tile)
  attn_fwd<<<dim3(512), 256, 0, stream>>>(QKVb, Vtb, AO);

  cvt_bf16<<<dim3(DM_ * DM_ / 1024), 256, 0, stream>>>(Wo, wbq, DM_ * DM_ / 4);
  gemm_bt<<<dim3(DM_ / BN, MT / BM), 256, 0, stream>>>(AO, wbq, out, MT, DM_, DM_);
}